// Round 9
// baseline (397.102 us; speedup 1.0000x reference)
//
#include <hip/hip_runtime.h>

#define D 64

static __host__ __device__ inline int alignup(int x) { return (x + 63) & ~63; }

__device__ inline float blo(unsigned int u) { return __uint_as_float(u << 16); }
__device__ inline float bhi(unsigned int u) { return __uint_as_float(u & 0xffff0000u); }
__device__ inline unsigned short f2b(float f) {
    unsigned int u = __float_as_uint(f);
    return (unsigned short)((u + 0x7FFFu + ((u >> 16) & 1u)) >> 16);
}
__device__ inline unsigned int packb(float lo, float hi) {
    return (unsigned int)f2b(lo) | ((unsigned int)f2b(hi) << 16);
}

__global__ void init_cnt(int* __restrict__ cnt, int n) {
    int i = blockIdx.x * blockDim.x + threadIdx.x;
    if (i < n) cnt[i] = 0;
}

// ONE atomic per edge: slot position within row + final counts.
__global__ void histo_pos(const int* __restrict__ row, int* __restrict__ cnt,
                          int* __restrict__ aux, int E) {
    int e = blockIdx.x * blockDim.x + threadIdx.x;
    if (e < E) aux[e] = atomicAdd(&cnt[row[e]], 1);
}

__global__ void convert_bf16(const float* __restrict__ x, unsigned short* __restrict__ xb, long nElem) {
    long t = (long)blockIdx.x * blockDim.x + threadIdx.x;
    long i = t * 4;
    if (i + 3 < nElem) {
        float4 v = *(const float4*)(x + i);
        ushort4 o;
        o.x = f2b(v.x); o.y = f2b(v.y); o.z = f2b(v.z); o.w = f2b(v.w);
        *(ushort4*)(xb + i) = o;
    } else {
        for (long k = i; k < nElem; ++k) xb[k] = f2b(x[k]);
    }
}

__global__ void scan_block_sums(const int* __restrict__ cnt, int* __restrict__ bsums, int n) {
    __shared__ int s[256];
    int t = threadIdx.x;
    int i = blockIdx.x * 256 + t;
    s[t] = (i < n) ? cnt[i] : 0;
    __syncthreads();
    for (int st = 128; st > 0; st >>= 1) {
        if (t < st) s[t] += s[t + st];
        __syncthreads();
    }
    if (t == 0) bsums[blockIdx.x] = s[0];
}

__global__ void scan_bsums(int* __restrict__ bsums, int nb) {
    __shared__ int s[1024];
    int t = threadIdx.x;
    s[t] = (t < nb) ? bsums[t] : 0;
    __syncthreads();
    for (int off = 1; off < 1024; off <<= 1) {
        int v = 0;
        if (t >= off) v = s[t - off];
        __syncthreads();
        if (t >= off) s[t] += v;
        __syncthreads();
    }
    if (t < nb) bsums[t] = (t == 0) ? 0 : s[t - 1];
}

// writes off[i] (exclusive prefix) and end[i] = off[i] + cnt[i]
__global__ void scan_final(const int* __restrict__ cnt, const int* __restrict__ bsums,
                           int* __restrict__ off, int* __restrict__ end, int n) {
    __shared__ int s[256];
    int t = threadIdx.x;
    int i = blockIdx.x * 256 + t;
    int v = (i < n) ? cnt[i] : 0;
    s[t] = v;
    __syncthreads();
    for (int o = 1; o < 256; o <<= 1) {
        int u = 0;
        if (t >= o) u = s[t - o];
        __syncthreads();
        if (t >= o) s[t] += u;
        __syncthreads();
    }
    if (i < n) {
        int o0 = bsums[blockIdx.x] + s[t] - v;
        off[i] = o0;
        end[i] = o0 + v;
    }
}

// atomic-free scatter: position known from histo. Stores RAW weight bits.
__global__ void reorder_csr(const int* __restrict__ row, const int* __restrict__ col,
                            const float* __restrict__ w, const int* __restrict__ off,
                            const int* __restrict__ aux, uint2* __restrict__ csr, int E) {
    int e = blockIdx.x * blockDim.x + threadIdx.x;
    if (e >= E) return;
    int r = row[e];
    uint2 ent;
    ent.x = (unsigned int)col[e];
    ent.y = __float_as_uint(w[e]);
    csr[off[r] + aux[e]] = ent;
}

// per-node: wdeg = fill + segment sum of raw w -> dinv = rsqrt
__global__ void seg_dinv(const uint2* __restrict__ csr, const int* __restrict__ off,
                         const int* __restrict__ end, float* __restrict__ dinv,
                         int n, float fill) {
    int i = blockIdx.x * blockDim.x + threadIdx.x;
    if (i >= n) return;
    float d = fill;
    int s = off[i], e = end[i];
    for (int p = s; p < e; ++p) d += __uint_as_float(csr[p].y);
    dinv[i] = d > 0.0f ? rsqrtf(d) : 0.0f;
}

// fold dinv[r]*dinv[c] into stored weights (dinv is L2-resident, 400KB)
__global__ void norm_w(uint2* __restrict__ csr, const int* __restrict__ off,
                       const int* __restrict__ end, const float* __restrict__ dinv, int n) {
    int i = blockIdx.x * blockDim.x + threadIdx.x;
    if (i >= n) return;
    float di = dinv[i];
    int s = off[i], e = end[i];
    for (int p = s; p < e; ++p) {
        uint2 ent = csr[p];
        float wn = __uint_as_float(ent.y) * di * dinv[(int)ent.x];
        ((float*)csr)[2 * p + 1] = wn;
    }
}

// 8 nodes per wave; group g (8 lanes) owns node wave*8+g; lane q owns columns
// 8q..8q+7. 16 entries per iteration: two coalesced uint2 loads, all 16
// gathers issued into static v[16] before any FMA (zero-weight gathers masked).
__global__ void hop_g8(const unsigned short* __restrict__ xb, const float* __restrict__ dinv,
                       const int* __restrict__ off, const int* __restrict__ end,
                       const uint2* __restrict__ csr,
                       unsigned short* __restrict__ outb, int n) {
    int t = blockIdx.x * blockDim.x + threadIdx.x;
    int wave = t >> 6;
    int lane = t & 63;
    int g = lane >> 3, q = lane & 7;
    int i = wave * 8 + g;
    bool active = i < n;
    int ii = active ? i : n - 1;

    const unsigned int* xw = (const unsigned int*)xb;
    float di = dinv[ii];
    float di2 = di * di;  // self-loop weight (fill=1): dinv^2
    uint4 sv = *(const uint4*)(xw + (long)ii * 32 + q * 4);
    float a0 = blo(sv.x) * di2, a1 = bhi(sv.x) * di2;
    float a2 = blo(sv.y) * di2, a3 = bhi(sv.y) * di2;
    float a4 = blo(sv.z) * di2, a5 = bhi(sv.z) * di2;
    float a6 = blo(sv.w) * di2, a7 = bhi(sv.w) * di2;

    int s = active ? off[ii] : 0;
    int e = active ? end[ii] : 0;

    for (int b = s; b < e; b += 16) {
        int i0 = b + q;     if (i0 >= e) i0 = e - 1;
        int i1 = b + 8 + q; if (i1 >= e) i1 = e - 1;
        uint2 e0 = csr[i0];
        uint2 e1 = csr[i1];
        uint4 v[16];
        float wv[16];
        #pragma unroll
        for (int j = 0; j < 16; ++j) {
            int srcl = g * 8 + (j & 7);
            int cb = __shfl((int)(j < 8 ? e0.x : e1.x), srcl, 64);
            float wj = __uint_as_float(__shfl((int)(j < 8 ? e0.y : e1.y), srcl, 64));
            if (b + j >= e) wj = 0.0f;
            wv[j] = wj;
            v[j] = make_uint4(0u, 0u, 0u, 0u);
            if (wj != 0.0f) v[j] = *(const uint4*)(xw + (long)cb * 32 + q * 4);
        }
        #pragma unroll
        for (int j = 0; j < 16; ++j) {
            float wj = wv[j];
            a0 += blo(v[j].x) * wj; a1 += bhi(v[j].x) * wj;
            a2 += blo(v[j].y) * wj; a3 += bhi(v[j].y) * wj;
            a4 += blo(v[j].z) * wj; a5 += bhi(v[j].z) * wj;
            a6 += blo(v[j].w) * wj; a7 += bhi(v[j].w) * wj;
        }
    }

    if (!active) return;
    uint4 o;
    o.x = packb(a0, a1); o.y = packb(a2, a3);
    o.z = packb(a4, a5); o.w = packb(a6, a7);
    *(uint4*)((unsigned int*)outb + (long)i * 32 + q * 4) = o;
}

// projection, shfl-free/LDS-free: lane l holds W[:,l] in 64 registers;
// per row: 16 uniform-address uint2 loads (wave-broadcast of bf16 h-row),
// 64 statically-indexed FMAs, one coalesced f32 store. Zero DS ops.
__global__ void proj_reg(const unsigned short* __restrict__ h2b,
                         const float* __restrict__ W, const float* __restrict__ bias,
                         float* __restrict__ out, int n) {
    int lane = threadIdx.x & 63;
    int wave = (blockIdx.x * blockDim.x + threadIdx.x) >> 6;
    int nW = (gridDim.x * blockDim.x) >> 6;

    float w[64];
    #pragma unroll
    for (int k = 0; k < 64; ++k) w[k] = W[k * D + lane];
    float bl = bias[lane];

    const uint2* h2 = (const uint2*)h2b;  // 4 bf16 per uint2
    for (int r = wave; r < n; r += nW) {
        const uint2* hr = h2 + (long)r * 16;
        float y0 = bl, y1 = 0.f, y2 = 0.f, y3 = 0.f;
        #pragma unroll
        for (int c = 0; c < 16; ++c) {
            uint2 hv = hr[c];  // uniform across wave -> broadcast
            y0 += blo(hv.x) * w[4 * c + 0];
            y1 += bhi(hv.x) * w[4 * c + 1];
            y2 += blo(hv.y) * w[4 * c + 2];
            y3 += bhi(hv.y) * w[4 * c + 3];
        }
        out[(long)r * D + lane] = (y0 + y1) + (y2 + y3);
    }
}

extern "C" void kernel_launch(void* const* d_in, const int* in_sizes, int n_in,
                              void* d_out, int out_size, void* d_ws, size_t ws_size,
                              hipStream_t stream) {
    const float* x    = (const float*)d_in[0];
    const int*   ei   = (const int*)d_in[1];
    const float* ew   = (const float*)d_in[2];
    const float* W    = (const float*)d_in[3];
    const float* bias = (const float*)d_in[4];

    int n = in_sizes[0] / D;   // 100000
    int E = in_sizes[2];       // 1600000
    const int* row = ei;
    const int* col = ei + E;

    float* out = (float*)d_out;

    // workspace layout (4-byte units)
    float* dinv  = (float*)d_ws;                  // n
    int*   cnt   = (int*)(dinv + alignup(n));     // n
    int*   bsums = cnt + alignup(n);              // <=1024
    int*   off   = bsums + 1024;                  // n
    int*   endp  = off + alignup(n);              // n
    int*   aux   = endp + alignup(n);             // E
    uint2* csr   = (uint2*)(aux + alignup(E));    // E x 8B
    unsigned short* xb  = (unsigned short*)(csr + alignup(E)); // n*D bf16
    unsigned short* h1b = xb + (long)alignup(n) * D;           // n*D bf16
    unsigned short* h2b = h1b + (long)alignup(n) * D;          // n*D bf16

    const float fill = 1.0f;  // IMPROVED = False
    const int blk = 256;
    int nbN = (n + blk - 1) / blk;
    int nbE = (E + blk - 1) / blk;

    init_cnt<<<nbN, blk, 0, stream>>>(cnt, n);
    histo_pos<<<nbE, blk, 0, stream>>>(row, cnt, aux, E);

    long nElem = (long)n * D;
    int nbC = (int)((nElem / 4 + blk - 1) / blk);
    convert_bf16<<<nbC, blk, 0, stream>>>(x, xb, nElem);

    scan_block_sums<<<nbN, blk, 0, stream>>>(cnt, bsums, n);
    scan_bsums<<<1, 1024, 0, stream>>>(bsums, nbN);
    scan_final<<<nbN, blk, 0, stream>>>(cnt, bsums, off, endp, n);

    reorder_csr<<<nbE, blk, 0, stream>>>(row, col, ew, off, aux, csr, E);
    seg_dinv<<<nbN, blk, 0, stream>>>(csr, off, endp, dinv, n, fill);
    norm_w<<<nbN, blk, 0, stream>>>(csr, off, endp, dinv, n);

    int nWaves = (n + 7) / 8;
    int nbHop = (nWaves * 64 + blk - 1) / blk;
    hop_g8<<<nbHop, blk, 0, stream>>>(xb, dinv, off, endp, csr, h1b, n);
    hop_g8<<<nbHop, blk, 0, stream>>>(h1b, dinv, off, endp, csr, h2b, n);

    proj_reg<<<2048, blk, 0, stream>>>(h2b, W, bias, out, n);
}